// Round 14
// baseline (1259.376 us; speedup 1.0000x reference)
//
#include <hip/hip_runtime.h>

typedef _Float16 half8 __attribute__((ext_vector_type(8)));
typedef float f32x4 __attribute__((ext_vector_type(4)));

#define TN    1000
#define TPAD  1024
#define NW    12          // u32 words per timestep (384 bits)
#define C2W   48          // c2 row stride (floats)

// ws layout:
//   wf16    @ 0         : 48*384 f16 = 36864 B   (padded fc_w, o>=35 zeroed)
//   spkbits @ 36864     : 256*1024*12 u32 = 12582912 B  (bit-packed spikes)
//   c2g     @ 12619776  : 256*1024*48 f32 = 50331648 B
#define WS_WF16   0
#define WS_SPK    36864
#define WS_C2     12619776

// ---------------- K0: cast fc_w to padded f16 ----------------
__global__ void k0_wcast(const float* __restrict__ fc_w, _Float16* __restrict__ wf16)
{
    int i = threadIdx.x + blockIdx.x * 256;
    if (i < 48 * 384) {
        int o = i / 384, k = i % 384;
        wf16[i] = (o < 35) ? (_Float16)fc_w[o * 384 + k] : (_Float16)0.f;
    }
}

// ---------------- K1: conv + LIF1 -> bit-packed spikes ----------------
// 1024 blocks = 256 b x 4 T-chunks (burn-in 128, validated by R12's numerics).
// 4 blocks/CU -> 24 waves/CU hides the global-load latency that pinned the
// R13 version (140us at 1 block/CU). Spikes exported via __ballot.
__global__ __launch_bounds__(384, 6) void k1_conv_lif1(
    const float* __restrict__ x, const float* __restrict__ conv_w,
    const float* __restrict__ conv_b, unsigned long long* __restrict__ spk64)
{
    const int tid = threadIdx.x;
    const int b = blockIdx.x >> 2;
    const int chunk = blockIdx.x & 3;
    const int wid = tid >> 6, lane = tid & 63;
    const int c = tid / 24, p = tid % 24;
    const int par = p & 1, pe = p - par;

    float wk8[8];
#pragma unroll
    for (int j = 0; j < 8; ++j) {
        int k = j - par;
        wk8[j] = (k >= 0 && k < 7) ? conv_w[c * 7 + k] : 0.f;
    }
    const float cb = conv_b[c];

    const int wLo = chunk * 250;
    const int wHi = (wLo + 250 < TN) ? wLo + 250 : TN;
    const int s0  = chunk ? (wLo - 128) : 0;
    const int nIt = chunk ? 24 : 16;       // x16 steps (extra steps gated/clamped)

    const float* xb = x + (size_t)b * (TN * 30) + pe;
    unsigned long long* sb = spk64 + (size_t)b * (TPAD * (NW / 2)) + wid;

    float m1 = 0.f, sp = 0.f;
    float2 XA[8][4], XB[8][4];

#define K1LOAD(X, BASE)                                                       \
    { _Pragma("unroll")                                                       \
      for (int s = 0; s < 8; ++s) {                                           \
          int t = (BASE) + s; t = (t < TN) ? t : (TN - 1);                    \
          const float2* p2 = (const float2*)(xb + (size_t)t * 30);            \
          X[s][0] = p2[0]; X[s][1] = p2[1]; X[s][2] = p2[2]; X[s][3] = p2[3]; \
      } }

#define K1COMP(X, BASE)                                                       \
    { _Pragma("unroll")                                                       \
      for (int s = 0; s < 8; ++s) {                                           \
          float c1 = cb;                                                      \
          c1 = fmaf(wk8[0], X[s][0].x, c1);  c1 = fmaf(wk8[1], X[s][0].y, c1);\
          c1 = fmaf(wk8[2], X[s][1].x, c1);  c1 = fmaf(wk8[3], X[s][1].y, c1);\
          c1 = fmaf(wk8[4], X[s][2].x, c1);  c1 = fmaf(wk8[5], X[s][2].y, c1);\
          c1 = fmaf(wk8[6], X[s][3].x, c1);  c1 = fmaf(wk8[7], X[s][3].y, c1);\
          m1 = fmaf(0.9f, m1, c1 - sp);                                       \
          sp = (m1 > 1.0f) ? 1.0f : 0.0f;                                     \
          int t = (BASE) + s;                                                 \
          if (t >= wLo && t < wHi) {   /* wave-uniform */                     \
              unsigned long long bal = __ballot(m1 > 1.0f);                   \
              if (lane == 0) sb[(size_t)t * (NW / 2)] = bal;                  \
          }                                                                   \
      } }

    int base = s0;
    K1LOAD(XA, base)
#pragma unroll 1
    for (int it = 0; it < nIt; ++it) {
        K1LOAD(XB, base + 8)
        K1COMP(XA, base)
        K1LOAD(XA, base + 16)
        K1COMP(XB, base + 8)
        base += 16;
    }
#undef K1LOAD
#undef K1COMP
}

// ---------------- K2: FC GEMM, no LDS, no barrier ----------------
// One wave = one 16-timestep tile x all 3 M-tiles. Lane loads its timestep's
// 12 bit-words (48B, 16B-aligned) and expands to B-fragments in registers;
// A reloaded per m from L2-hot wf16. 16384 independent wave-tiles.
__global__ __launch_bounds__(256, 3) void k2_gemm(
    const unsigned* __restrict__ spkbits, const _Float16* __restrict__ wf16,
    float* __restrict__ c2g)
{
    const int W = (blockIdx.x << 2) + (threadIdx.x >> 6);   // 0..16383
    const int lane = threadIdx.x & 63;
    const int b = W >> 6, tile = W & 63;
    const int nL = lane & 15, q = lane >> 4;
    const int t = tile * 16 + nL;

    const uint4* src = (const uint4*)(spkbits + ((size_t)b * TPAD + t) * NW);
    uint4 wa = src[0], wb = src[1], wc = src[2];
    unsigned words[12] = {wa.x, wa.y, wa.z, wa.w, wb.x, wb.y, wb.z, wb.w,
                          wc.x, wc.y, wc.z, wc.w};

    half8 B[12];
#pragma unroll
    for (int kt = 0; kt < 12; ++kt) {
        unsigned bt = (words[kt] >> (8 * q)) & 0xFFu;
        unsigned v[4];
#pragma unroll
        for (int j = 0; j < 4; ++j)
            v[j] = (((bt >> (2 * j)) & 1u) ? 0x3C00u : 0u) |
                   (((bt >> (2 * j + 1)) & 1u) ? 0x3C000000u : 0u);
        union { unsigned u[4]; half8 h; } cv;
        cv.u[0] = v[0]; cv.u[1] = v[1]; cv.u[2] = v[2]; cv.u[3] = v[3];
        B[kt] = cv.h;
    }

    float* cdst = c2g + ((size_t)b * TPAD + t) * C2W + q * 4;
#pragma unroll
    for (int m = 0; m < 3; ++m) {
        const _Float16* wp = wf16 + (m * 16 + nL) * 384 + q * 8;
        half8 A[12];
#pragma unroll
        for (int kt = 0; kt < 12; ++kt)
            A[kt] = *(const half8*)(wp + kt * 32);
        f32x4 acc = {0.f, 0.f, 0.f, 0.f};
#pragma unroll
        for (int kt = 0; kt < 12; ++kt)
            acc = __builtin_amdgcn_mfma_f32_16x16x32_f16(A[kt], B[kt], acc, 0, 0, 0);
        // C/D: col = lane&15 (t_local), row = q*4+i (o_local)
        *(f32x4*)(cdst + m * 16) = acc;
    }
}

// ---------------- K3: LIF2 scan + mean, 4 T-chunks/b with mem2 burn-in ----------------
__global__ __launch_bounds__(256, 1) void k3_scan(
    const float* __restrict__ c2g, const float* __restrict__ fc_b,
    float* __restrict__ out)
{
    const int b = blockIdx.x;
    const int w = threadIdx.x >> 6, lane = threadIdx.x & 63;
    const bool act = lane < 35;
    const float fcb = act ? fc_b[lane] : 0.f;
    const int aLo = w * 250;
    const int aHi = (aLo + 250 < TN) ? aLo + 250 : TN;
    const int s0  = w ? (aLo - 128) : 0;
    const int nIt = w ? 24 : 16;
    const float* cs = c2g + (size_t)b * TPAD * C2W + (act ? lane : 0);

    float mem2 = 0.f, accO = 0.f;
    float VA[8], VB[8];

#define K3LOAD(V, BASE)                                                       \
    { _Pragma("unroll")                                                       \
      for (int j = 0; j < 8; ++j) V[j] = cs[(size_t)((BASE) + j) * C2W]; }

#define K3COMP(V, BASE)                                                       \
    { _Pragma("unroll")                                                       \
      for (int j = 0; j < 8; ++j) {                                           \
          float r2 = (mem2 > 1.0f) ? 1.0f : 0.0f;                             \
          mem2 = 0.9f * mem2 + (V[j] + fcb) - r2;                             \
          int t = (BASE) + j;                                                 \
          if (t >= aLo && t < aHi) accO += mem2;                              \
      } }

    int base = s0;
    K3LOAD(VA, base)
#pragma unroll 1
    for (int it = 0; it < nIt; ++it) {
        K3LOAD(VB, base + 8)
        K3COMP(VA, base)
        K3LOAD(VA, base + 16)
        K3COMP(VB, base + 8)
        base += 16;
    }
#undef K3LOAD
#undef K3COMP

    if (act) atomicAdd(&out[b * 35 + lane], accO * (1.0f / (float)TN));
}

extern "C" void kernel_launch(void* const* d_in, const int* in_sizes, int n_in,
                              void* d_out, int out_size, void* d_ws, size_t ws_size,
                              hipStream_t stream) {
    const float* x      = (const float*)d_in[0];
    const float* conv_w = (const float*)d_in[1];
    const float* conv_b = (const float*)d_in[2];
    const float* fc_w   = (const float*)d_in[3];
    const float* fc_b   = (const float*)d_in[4];
    float* out          = (float*)d_out;

    char* ws = (char*)d_ws;
    _Float16*           wf16    = (_Float16*)(ws + WS_WF16);
    unsigned*           spkbits = (unsigned*)(ws + WS_SPK);
    unsigned long long* spk64   = (unsigned long long*)(ws + WS_SPK);
    float*              c2g     = (float*)(ws + WS_C2);

    hipMemsetAsync(out, 0, (size_t)out_size * sizeof(float), stream);
    k0_wcast    <<<72,   256, 0, stream>>>(fc_w, wf16);
    k1_conv_lif1<<<1024, 384, 0, stream>>>(x, conv_w, conv_b, spk64);
    k2_gemm     <<<4096, 256, 0, stream>>>(spkbits, wf16, c2g);
    k3_scan     <<<256,  256, 0, stream>>>(c2g, fc_b, out);
}

// Round 15
// 238.977 us; speedup vs baseline: 5.2699x; 5.2699x over previous
//
#include <hip/hip_runtime.h>

typedef _Float16 half8 __attribute__((ext_vector_type(8)));
typedef float f32x4 __attribute__((ext_vector_type(4)));

#define TN    1000
#define TPAD  1024
#define NW    12          // u32 words per timestep (384 bits, even/odd interleaved per 128-group)
#define C2W   48          // c2 row stride (floats)
#define SPH   32          // K1 staging phase length
#define XSW   32          // K1 xs row stride (floats)

// ws layout:
//   wf16    @ 0         : 48*384 f16 = 36864 B   (padded fc_w, o>=35 zeroed)
//   spkbits @ 36864     : 256*1024*12 u32 = 12582912 B  (bit-packed spikes)
//   c2g     @ 12619776  : 256*1024*48 f32 = 50331648 B
#define WS_WF16   0
#define WS_SPK    36864
#define WS_C2     12619776

// ---------------- K0: cast fc_w to padded f16 ----------------
__global__ void k0_wcast(const float* __restrict__ fc_w, _Float16* __restrict__ wf16)
{
    int i = threadIdx.x + blockIdx.x * 256;
    if (i < 48 * 384) {
        int o = i / 384, k = i % 384;
        wf16[i] = (o < 35) ? (_Float16)fc_w[o * 384 + k] : (_Float16)0.f;
    }
}

// ---------------- K1: conv + LIF1 -> bit-packed spikes ----------------
// R5's proven conv pipeline, standalone: 192 thr (c=tid/12, u=tid%12; positions
// 2u,2u+1), LDS x-staging with bulk xr[5] loads (the only VMEM pattern that has
// reliably pipelined: R5/R12), 1024 blocks = 256 b x 4 T-chunks (128-step
// burn-in, numerically validated R12/R14). launch_bounds(192,3): VGPR cap ~170,
// need ~90 -> NO spill (R14's failure mode). Spikes: 2 ballots/step -> one
// 16B ulonglong2 store per wave-step. Word layout: group g=neurons[128g,128g+128):
// W[2g]=even neurons (bit L = neuron 128g+2L), W[2g+1]=odd.
__global__ __launch_bounds__(192, 3) void k1_conv_lif1(
    const float* __restrict__ x, const float* __restrict__ conv_w,
    const float* __restrict__ conv_b, unsigned long long* __restrict__ spk64)
{
    __shared__ float xs[2][SPH][XSW];   // 8192 B

    const int tid = threadIdx.x;
    const int b = blockIdx.x >> 2;
    const int chunk = blockIdx.x & 3;
    const int wid = tid >> 6, lane = tid & 63;
    const int c = tid / 12, u = tid % 12;

    float wk[7];
#pragma unroll
    for (int k = 0; k < 7; ++k) wk[k] = conv_w[c * 7 + k];
    const float cb = conv_b[c];

    const int wLo = chunk * 250;
    const int wHi = (wLo + 250 < TN) ? (wLo + 250) : TN;
    const int s0  = chunk ? (wLo - 128) : 0;
    const int nPh = chunk ? 12 : 8;          // 384 / 256 staged steps

    const float* xb = x + (size_t)b * (TN * 30);
    unsigned long long* sb = spk64 + (size_t)b * (TPAD * 6) + 2 * wid;

    float m10 = 0.f, m11 = 0.f, sp0 = 0.f, sp1 = 0.f;

    // prologue: stage phase 0 (t = s0..s0+31, all < TN)
#pragma unroll
    for (int r = 0; r < 5; ++r) {
        int f = tid + 192 * r;               // 0..959
        xs[0][f / 30][f % 30] = xb[(size_t)(s0 + f / 30) * 30 + (f % 30)];
    }
    __syncthreads();

#pragma unroll 1
    for (int ph = 0; ph < nPh; ++ph) {
        const int tb = s0 + ph * SPH;
        float xr[5];
        const bool stg = (ph < nPh - 1);
        if (stg) {                           // bulk loads for phase ph+1
#pragma unroll
            for (int r = 0; r < 5; ++r) {
                int f = tid + 192 * r;
                int t = tb + SPH + f / 30;
                xr[r] = (t < TN) ? xb[(size_t)t * 30 + (f % 30)] : 0.f;
            }
        }
        {
            const float* xrow = &xs[ph & 1][0][2 * u];
#pragma unroll 4
            for (int s = 0; s < SPH; ++s) {
                const float2* x2 = (const float2*)(xrow + s * XSW);
                float2 a0 = x2[0], a1 = x2[1], a2 = x2[2], a3 = x2[3];
                float c1a = cb, c1b = cb;
                c1a = fmaf(wk[0], a0.x, c1a);  c1b = fmaf(wk[0], a0.y, c1b);
                c1a = fmaf(wk[1], a0.y, c1a);  c1b = fmaf(wk[1], a1.x, c1b);
                c1a = fmaf(wk[2], a1.x, c1a);  c1b = fmaf(wk[2], a1.y, c1b);
                c1a = fmaf(wk[3], a1.y, c1a);  c1b = fmaf(wk[3], a2.x, c1b);
                c1a = fmaf(wk[4], a2.x, c1a);  c1b = fmaf(wk[4], a2.y, c1b);
                c1a = fmaf(wk[5], a2.y, c1a);  c1b = fmaf(wk[5], a3.x, c1b);
                c1a = fmaf(wk[6], a3.x, c1a);  c1b = fmaf(wk[6], a3.y, c1b);

                m10 = fmaf(0.9f, m10, c1a - sp0);
                m11 = fmaf(0.9f, m11, c1b - sp1);
                sp0 = (m10 > 1.0f) ? 1.0f : 0.0f;
                sp1 = (m11 > 1.0f) ? 1.0f : 0.0f;

                unsigned long long bal0 = __ballot(m10 > 1.0f);
                unsigned long long bal1 = __ballot(m11 > 1.0f);
                int t = tb + s;
                if (t >= wLo && t < wHi && lane == 0) {
                    ulonglong2 v; v.x = bal0; v.y = bal1;
                    *(ulonglong2*)(sb + (size_t)t * 6) = v;
                }
            }
        }
        if (stg) {
            float* dst = &xs[(ph + 1) & 1][0][0];
#pragma unroll
            for (int r = 0; r < 5; ++r) {
                int f = tid + 192 * r;
                dst[(f / 30) * XSW + (f % 30)] = xr[r];
            }
        }
        __syncthreads();
    }
}

// ---------------- K2: FC GEMM, no LDS, no barrier ----------------
// One wave = one 16-timestep tile x all 3 M-tiles. Lane loads its timestep's
// 12 bit-words (48B, 3 uint4) and expands to B-fragments in registers using
// the even/odd interleaved layout; A from L2-hot wf16.
__global__ __launch_bounds__(256, 3) void k2_gemm(
    const unsigned* __restrict__ spkbits, const _Float16* __restrict__ wf16,
    float* __restrict__ c2g)
{
    const int W = (blockIdx.x << 2) + (threadIdx.x >> 6);   // 0..16383
    const int lane = threadIdx.x & 63;
    const int b = W >> 6, tile = W & 63;
    const int nL = lane & 15, q = lane >> 4;
    const int t = tile * 16 + nL;

    const uint4* src = (const uint4*)(spkbits + ((size_t)b * TPAD + t) * NW);
    uint4 wa = src[0], wb = src[1], wc = src[2];
    unsigned long long W64[6];
    W64[0] = (unsigned long long)wa.x | ((unsigned long long)wa.y << 32);
    W64[1] = (unsigned long long)wa.z | ((unsigned long long)wa.w << 32);
    W64[2] = (unsigned long long)wb.x | ((unsigned long long)wb.y << 32);
    W64[3] = (unsigned long long)wb.z | ((unsigned long long)wb.w << 32);
    W64[4] = (unsigned long long)wc.x | ((unsigned long long)wc.y << 32);
    W64[5] = (unsigned long long)wc.z | ((unsigned long long)wc.w << 32);

    half8 B[12];
#pragma unroll
    for (int kt = 0; kt < 12; ++kt) {
        const int base = kt * 32 + q * 8;        // even, never crosses 128-grp in +7
        const int grp  = base >> 7;              // 0..2 (runtime via q)
        const int pos0 = (base & 127) >> 1;
        const unsigned long long We = W64[grp * 2];
        const unsigned long long Wo = W64[grp * 2 + 1];
        unsigned uu[4];
#pragma unroll
        for (int jj = 0; jj < 4; ++jj) {
            unsigned b0 = (unsigned)((We >> (pos0 + jj)) & 1ull);
            unsigned b1 = (unsigned)((Wo >> (pos0 + jj)) & 1ull);
            uu[jj] = (b0 ? 0x3C00u : 0u) | (b1 ? 0x3C000000u : 0u);
        }
        union { unsigned u[4]; half8 h; } cv;
        cv.u[0] = uu[0]; cv.u[1] = uu[1]; cv.u[2] = uu[2]; cv.u[3] = uu[3];
        B[kt] = cv.h;
    }

    float* cdst = c2g + ((size_t)b * TPAD + t) * C2W + q * 4;
#pragma unroll
    for (int m = 0; m < 3; ++m) {
        const _Float16* wp = wf16 + (m * 16 + nL) * 384 + q * 8;
        half8 A[12];
#pragma unroll
        for (int kt = 0; kt < 12; ++kt)
            A[kt] = *(const half8*)(wp + kt * 32);
        f32x4 acc = {0.f, 0.f, 0.f, 0.f};
#pragma unroll
        for (int kt = 0; kt < 12; ++kt)
            acc = __builtin_amdgcn_mfma_f32_16x16x32_f16(A[kt], B[kt], acc, 0, 0, 0);
        // C/D: col = lane&15 (t_local), row = q*4+i (o_local)
        *(f32x4*)(cdst + m * 16) = acc;
    }
}

// ---------------- K3: LIF2 scan + mean, 4 T-chunks/b with mem2 burn-in ----------------
__global__ __launch_bounds__(256, 1) void k3_scan(
    const float* __restrict__ c2g, const float* __restrict__ fc_b,
    float* __restrict__ out)
{
    const int b = blockIdx.x;
    const int w = threadIdx.x >> 6, lane = threadIdx.x & 63;
    const bool act = lane < 35;
    const float fcb = act ? fc_b[lane] : 0.f;
    const int aLo = w * 250;
    const int aHi = (aLo + 250 < TN) ? aLo + 250 : TN;
    const int s0  = w ? (aLo - 128) : 0;
    const int nIt = w ? 24 : 16;
    const float* cs = c2g + (size_t)b * TPAD * C2W + (act ? lane : 0);

    float mem2 = 0.f, accO = 0.f;
    float VA[8], VB[8];

#define K3LOAD(V, BASE)                                                       \
    { _Pragma("unroll")                                                       \
      for (int j = 0; j < 8; ++j) V[j] = cs[(size_t)((BASE) + j) * C2W]; }

#define K3COMP(V, BASE)                                                       \
    { _Pragma("unroll")                                                       \
      for (int j = 0; j < 8; ++j) {                                           \
          float r2 = (mem2 > 1.0f) ? 1.0f : 0.0f;                             \
          mem2 = 0.9f * mem2 + (V[j] + fcb) - r2;                             \
          int t = (BASE) + j;                                                 \
          if (t >= aLo && t < aHi) accO += mem2;                              \
      } }

    int base = s0;
    K3LOAD(VA, base)
#pragma unroll 1
    for (int it = 0; it < nIt; ++it) {
        K3LOAD(VB, base + 8)
        K3COMP(VA, base)
        K3LOAD(VA, base + 16)
        K3COMP(VB, base + 8)
        base += 16;
    }
#undef K3LOAD
#undef K3COMP

    if (act) atomicAdd(&out[b * 35 + lane], accO * (1.0f / (float)TN));
}

extern "C" void kernel_launch(void* const* d_in, const int* in_sizes, int n_in,
                              void* d_out, int out_size, void* d_ws, size_t ws_size,
                              hipStream_t stream) {
    const float* x      = (const float*)d_in[0];
    const float* conv_w = (const float*)d_in[1];
    const float* conv_b = (const float*)d_in[2];
    const float* fc_w   = (const float*)d_in[3];
    const float* fc_b   = (const float*)d_in[4];
    float* out          = (float*)d_out;

    char* ws = (char*)d_ws;
    _Float16*           wf16    = (_Float16*)(ws + WS_WF16);
    unsigned*           spkbits = (unsigned*)(ws + WS_SPK);
    unsigned long long* spk64   = (unsigned long long*)(ws + WS_SPK);
    float*              c2g     = (float*)(ws + WS_C2);

    hipMemsetAsync(out, 0, (size_t)out_size * sizeof(float), stream);
    k0_wcast    <<<72,   256, 0, stream>>>(fc_w, wf16);
    k1_conv_lif1<<<1024, 192, 0, stream>>>(x, conv_w, conv_b, spk64);
    k2_gemm     <<<4096, 256, 0, stream>>>(spkbits, wf16, c2g);
    k3_scan     <<<256,  256, 0, stream>>>(c2g, fc_b, out);
}